// Round 18
// baseline (483.057 us; speedup 1.0000x reference)
//
#include <hip/hip_runtime.h>

// Self-attention B=2, S=4096, D=1024, fp32 in/out.
//
// Round-18: dispatch-count + TLP consolidation.
//   * Tier A (ws >= 190,840,832 B): per-batch buffers for Eh/El/QM/Vt ->
//     split32 runs ONCE over both batches (grid 8192), QM and Vt become
//     z=2 dispatches (grid 1024 = more blocks/CU). 16 -> 13 dispatches.
//     Vt de-aliased from QM. gemm_bt gains z-strides (0 = unbatched).
//   * Tier B (fallback): round-17 launcher exactly (no regression).
//   * Vt -> KU=4 (48KB LDS) in both tiers.
//   * gemm8s (96.3us, conflicts=0) and softmax untouched (controls).
// Algebra unchanged: QM trick + split-bf16 {hh,hl,lh}; XOR-swizzled LDS;
// bf16 maskT epilogue; BM=64 TLP tiles; KU=2 SPLIT / KU=4 plain engines.

#define S_LEN 4096

typedef __bf16 bf16x8 __attribute__((ext_vector_type(8)));
typedef float f32x4 __attribute__((ext_vector_type(4)));

__device__ __forceinline__ unsigned short f2bf(float x) {
  unsigned u = __float_as_uint(x);
  unsigned r = u + 0x7fffu + ((u >> 16) & 1u);  // round-to-nearest-even
  return (unsigned short)(r >> 16);
}
__device__ __forceinline__ float bf2f(unsigned short h) {
  return __uint_as_float(((unsigned)h) << 16);
}

__device__ __forceinline__ void gl_lds16(const void* g, void* l) {
  __builtin_amdgcn_global_load_lds(
      (const __attribute__((address_space(1))) void*)g,
      (__attribute__((address_space(3))) void*)l, 16, 0, 0);
}

// ---------------------------------------------------------------------------
// split32: fp32 -> (hi, lo) bf16 pair, elementwise, float4-vectorized.
// grid*256*4 must equal the element count (works across batches if contiguous).
__launch_bounds__(256)
__global__ void split32(const float* __restrict__ e,
                        unsigned short* __restrict__ Eh,
                        unsigned short* __restrict__ El) {
  int i = blockIdx.x * 256 + threadIdx.x;  // float4 index
  float4 v = reinterpret_cast<const float4*>(e)[i];
  ushort4 h, l;
  h.x = f2bf(v.x); l.x = f2bf(v.x - bf2f(h.x));
  h.y = f2bf(v.y); l.y = f2bf(v.y - bf2f(h.y));
  h.z = f2bf(v.z); l.z = f2bf(v.z - bf2f(h.z));
  h.w = f2bf(v.w); l.w = f2bf(v.w - bf2f(h.w));
  reinterpret_cast<ushort4*>(Eh)[i] = h;
  reinterpret_cast<ushort4*>(El)[i] = l;
}

// splitW: wq and wk hi/lo split in one dispatch (grid 2048; 262144 float4 each).
__launch_bounds__(256)
__global__ void splitW(const float* __restrict__ wq, const float* __restrict__ wk,
                       unsigned short* __restrict__ WqH, unsigned short* __restrict__ WqL,
                       unsigned short* __restrict__ WkH, unsigned short* __restrict__ WkL) {
  int i = blockIdx.x * 256 + threadIdx.x;
  const bool isQ = (i < 262144);
  const float* s = isQ ? wq : wk;
  unsigned short* H = isQ ? WqH : WkH;
  unsigned short* L = isQ ? WqL : WkL;
  int j = isQ ? i : i - 262144;
  float4 v = reinterpret_cast<const float4*>(s)[j];
  ushort4 h, l;
  h.x = f2bf(v.x); l.x = f2bf(v.x - bf2f(h.x));
  h.y = f2bf(v.y); l.y = f2bf(v.y - bf2f(h.y));
  h.z = f2bf(v.z); l.z = f2bf(v.z - bf2f(h.z));
  h.w = f2bf(v.w); l.w = f2bf(v.w - bf2f(h.w));
  reinterpret_cast<ushort4*>(H)[j] = h;
  reinterpret_cast<ushort4*>(L)[j] = l;
}

// ---------------------------------------------------------------------------
// prep_wv: Wv[d][e] -> Wvt[e][d] plain bf16. 32x32 LDS transpose.
__launch_bounds__(256)
__global__ void prep_wv(const float* __restrict__ wv, unsigned short* __restrict__ Wvt) {
  __shared__ float tile[32][33];
  const int bx = blockIdx.x * 32;
  const int by = blockIdx.y * 32;
  const int tx = threadIdx.x;
  const int ty = threadIdx.y;
#pragma unroll
  for (int j = 0; j < 4; ++j)
    tile[ty + j * 8][tx] = wv[(long)(by + ty + j * 8) * 1024 + bx + tx];
  __syncthreads();
#pragma unroll
  for (int j = 0; j < 4; ++j) {
    float v = tile[tx][ty + j * 8];
    Wvt[(long)(bx + ty + j * 8) * 1024 + by + tx] = f2bf(v);
  }
}

// ---------------------------------------------------------------------------
// prep_maskT: maskT[q][k] = bf16(mask_filled[k][q]), mask==0 -> -inf (0xFF80).
__launch_bounds__(256)
__global__ void prep_maskT(const float* __restrict__ mask,
                           unsigned short* __restrict__ maskT) {
  __shared__ float tile[32][33];
  const int bx = blockIdx.x * 32;  // q block
  const int by = blockIdx.y * 32;  // k block
  const int tx = threadIdx.x;
  const int ty = threadIdx.y;
#pragma unroll
  for (int j = 0; j < 4; ++j)
    tile[ty + j * 8][tx] = mask[(long)(by + ty + j * 8) * S_LEN + bx + tx];
  __syncthreads();
#pragma unroll
  for (int j = 0; j < 4; ++j) {
    float v = tile[tx][ty + j * 8];  // = mask[by+tx][bx+ty+j*8]
    unsigned short u = (v == 0.0f) ? (unsigned short)0xFF80 : f2bf(v);
    maskT[(long)(bx + ty + j * 8) * S_LEN + by + tx] = u;
  }
}

// ---------------------------------------------------------------------------
// BMx128 engine: NT GEMM with XOR-swizzled LDS. KU = K-unroll, BM in {64,128}.
// 4 waves: wave tile (BM/2) x 64. z-strides (elements) for batched dispatch.
// MODE 0: hi/lo pair  MODE 2: bf16  MODE 3: f32.
template <int SPLIT, int MODE, int KU, int BM>
__launch_bounds__(256)
__global__ void gemm_bt(const unsigned short* __restrict__ Ah,
                        const unsigned short* __restrict__ Al, int lda,
                        const unsigned short* __restrict__ Bh,
                        const unsigned short* __restrict__ Bl, int ldb,
                        void* __restrict__ Cp, int ldc,
                        unsigned short* __restrict__ C2, int kIters,
                        long zA, long zB, long zC) {
  constexpr int NMI = BM / 32;        // fragment rows per wave (4 or 2)
  __shared__ unsigned short lAh[KU * BM * 32];
  __shared__ unsigned short lBh[KU * 128 * 32];
  __shared__ unsigned short lAl[SPLIT ? KU * BM * 32 : 8];   // KU-scaled
  __shared__ unsigned short lBl[SPLIT ? KU * 128 * 32 : 8];

  const int t = threadIdx.x;
  const int w = t >> 6;
  const int lane = t & 63;
  const int g = lane >> 4;
  const int r = lane & 15;
  const int wm = (w >> 1) * (BM / 2);
  const int wn = (w & 1) * 64;
  const long bm = (long)blockIdx.x * BM;
  const long bn = (long)blockIdx.y * 128;
  const long az = (long)blockIdx.z * zA;
  const long bz = (long)blockIdx.z * zB;
  const long cz = (long)blockIdx.z * zC;
  const unsigned short* A0 = Ah + az;
  const unsigned short* A1 = SPLIT ? (Al + az) : nullptr;
  const unsigned short* B0 = Bh + bz;
  const unsigned short* B1 = SPLIT ? (Bl + bz) : nullptr;

  f32x4 acc[NMI][4];
  const f32x4 vzero = {0.f, 0.f, 0.f, 0.f};
#pragma unroll
  for (int mi = 0; mi < NMI; ++mi)
#pragma unroll
    for (int ni = 0; ni < 4; ++ni) acc[mi][ni] = vzero;

  const int outer = kIters / KU;
  for (int kt = 0; kt < outer; ++kt) {
    __syncthreads();
    const long kbase = (long)kt * 32 * KU;
#pragma unroll
    for (int u = 0; u < KU; ++u) {
      // A tile: BM*4 granules (1 or 2 passes of 256 threads)
#pragma unroll
      for (int i = 0; i < BM * 4 / 256; ++i) {
        int s = i * 256 + t;
        int row = s >> 2;
        int ko = (s & 3) ^ ((row >> 1) & 3);
        long goffA = (bm + row) * (long)lda + kbase + u * 32 + ko * 8;
        int lbase = u * (BM * 32) + i * 2048 + w * 512;
        gl_lds16(A0 + goffA, lAh + lbase);
        if constexpr (SPLIT) gl_lds16(A1 + goffA, lAl + lbase);
      }
      // B tile: 512 granules (2 passes)
#pragma unroll
      for (int i = 0; i < 2; ++i) {
        int s = i * 256 + t;
        int row = s >> 2;
        int ko = (s & 3) ^ ((row >> 1) & 3);
        long goffB = (bn + row) * (long)ldb + kbase + u * 32 + ko * 8;
        int lbase = u * 4096 + i * 2048 + w * 512;
        gl_lds16(B0 + goffB, lBh + lbase);
        if constexpr (SPLIT) gl_lds16(B1 + goffB, lBl + lbase);
      }
    }
    __syncthreads();

#pragma unroll
    for (int u = 0; u < KU; ++u) {
      bf16x8 af[NMI], bfh[4], af2[NMI], bf2v[4];
#pragma unroll
      for (int mi = 0; mi < NMI; ++mi) {
        int rowa = wm + mi * 16 + r;
        int o = u * (BM * 32) + rowa * 32 + ((g ^ ((rowa >> 1) & 3)) * 8);
        af[mi] = *reinterpret_cast<const bf16x8*>(&lAh[o]);
        if constexpr (SPLIT)
          af2[mi] = *reinterpret_cast<const bf16x8*>(&lAl[o]);
      }
#pragma unroll
      for (int ni = 0; ni < 4; ++ni) {
        int rowb = wn + ni * 16 + r;
        int o = u * 4096 + rowb * 32 + ((g ^ ((rowb >> 1) & 3)) * 8);
        bfh[ni] = *reinterpret_cast<const bf16x8*>(&lBh[o]);
        if constexpr (SPLIT)
          bf2v[ni] = *reinterpret_cast<const bf16x8*>(&lBl[o]);
      }
#pragma unroll
      for (int mi = 0; mi < NMI; ++mi)
#pragma unroll
        for (int ni = 0; ni < 4; ++ni) {
          acc[mi][ni] = __builtin_amdgcn_mfma_f32_16x16x32_bf16(af[mi], bfh[ni], acc[mi][ni], 0, 0, 0);
          if constexpr (SPLIT) {
            acc[mi][ni] = __builtin_amdgcn_mfma_f32_16x16x32_bf16(af[mi], bf2v[ni], acc[mi][ni], 0, 0, 0);
            acc[mi][ni] = __builtin_amdgcn_mfma_f32_16x16x32_bf16(af2[mi], bfh[ni], acc[mi][ni], 0, 0, 0);
          }
        }
    }
  }

#pragma unroll
  for (int mi = 0; mi < NMI; ++mi) {
#pragma unroll
    for (int ni = 0; ni < 4; ++ni) {
      long row0 = bm + wm + mi * 16 + g * 4;
      long col = bn + wn + ni * 16 + r;
#pragma unroll
      for (int q = 0; q < 4; ++q) {
        float v = acc[mi][ni][q];
        long row = row0 + q;
        if constexpr (MODE == 0) {
          unsigned short h = f2bf(v);
          ((unsigned short*)Cp)[cz + row * (long)ldc + col] = h;
          C2[cz + row * (long)ldc + col] = f2bf(v - bf2f(h));
        } else if constexpr (MODE == 2) {
          ((unsigned short*)Cp)[cz + row * (long)ldc + col] = f2bf(v);
        } else {
          ((float*)Cp)[cz + row * (long)ldc + col] = v;
        }
      }
    }
  }
}

// ---------------------------------------------------------------------------
// Scores kernel (round-15-proven, 16x16x32): 256^2, 8 waves (2M x 4N),
// BK=32, 2-stage LDS dbuf, 4 phases/K-step, staging A@p0 B@p1.
__launch_bounds__(512, 2)
__global__ void gemm8s(const unsigned short* __restrict__ Ah,
                       const unsigned short* __restrict__ Al, int lda,
                       const unsigned short* __restrict__ Bh,
                       const unsigned short* __restrict__ Bl, int ldb,
                       float* __restrict__ C, int ldc,
                       const float* __restrict__ mask,
                       const unsigned short* __restrict__ maskT,
                       float scale, int nkt) {
  __shared__ __align__(16) unsigned short lds[4][2][8192];

  const int t = threadIdx.x;          // 0..511
  const int w = t >> 6;               // wave 0..7
  const int lane = t & 63;
  const int g = lane >> 4;
  const int r = lane & 15;
  const int wr = w >> 2;              // 0..1  (M)
  const int wc = w & 3;               // 0..3  (N)
  const long bm = (long)blockIdx.x * 256;
  const long bn = (long)blockIdx.y * 256;

  const int row0 = t >> 2;
  const int ko = (t & 3) ^ ((t >> 3) & 3);
  const unsigned short* pAh = Ah + (bm + row0) * (long)lda + ko * 8;
  const unsigned short* pAl = Al + (bm + row0) * (long)lda + ko * 8;
  const unsigned short* pBh = Bh + (bn + row0) * (long)ldb + ko * 8;
  const unsigned short* pBl = Bl + (bn + row0) * (long)ldb + ko * 8;

  f32x4 acc[8][4];
  const f32x4 vzero = {0.f, 0.f, 0.f, 0.f};
#pragma unroll
  for (int mi = 0; mi < 8; ++mi)
#pragma unroll
    for (int ni = 0; ni < 4; ++ni) acc[mi][ni] = vzero;

  // Prologue: stage K-step 0 into buf 0.
#pragma unroll
  for (int T = 0; T < 4; ++T) {
    const unsigned short* sp = (T == 0) ? pAh : (T == 1) ? pAl : (T == 2) ? pBh : pBl;
    long ld = (T < 2) ? lda : ldb;
    gl_lds16(sp, &lds[T][0][w * 512]);
    gl_lds16(sp + 128 * ld, &lds[T][0][4096 + w * 512]);
  }
  asm volatile("s_waitcnt vmcnt(0)" ::: "memory");
  __syncthreads();

  for (int kt = 0; kt < nkt; ++kt) {
    const int cb = kt & 1, nb = cb ^ 1;
    const bool stg = (kt < nkt - 1);
    bf16x8 bh[4], bl[4];
#pragma unroll
    for (int p = 0; p < 4; ++p) {
      if (p == 0) {
#pragma unroll
        for (int ni = 0; ni < 4; ++ni) {
          int rowb = wc * 64 + ni * 16 + r;
          int o = rowb * 32 + ((g ^ ((rowb >> 1) & 3)) * 8);
          bh[ni] = *reinterpret_cast<const bf16x8*>(&lds[2][cb][o]);
          bl[ni] = *reinterpret_cast<const bf16x8*>(&lds[3][cb][o]);
        }
      }
      bf16x8 ah[2], al[2];
#pragma unroll
      for (int i = 0; i < 2; ++i) {
        int rowa = wr * 128 + (2 * p + i) * 16 + r;
        int o = rowa * 32 + ((g ^ ((rowa >> 1) & 3)) * 8);
        ah[i] = *reinterpret_cast<const bf16x8*>(&lds[0][cb][o]);
        al[i] = *reinterpret_cast<const bf16x8*>(&lds[1][cb][o]);
      }
      // Staging: A tiles at phase 0, B tiles at phase 1 (round-9-proven).
      if (stg && p == 0) {
        gl_lds16(pAh + 32, &lds[0][nb][w * 512]);
        gl_lds16(pAh + 32 + 128 * (long)lda, &lds[0][nb][4096 + w * 512]);
        gl_lds16(pAl + 32, &lds[1][nb][w * 512]);
        gl_lds16(pAl + 32 + 128 * (long)lda, &lds[1][nb][4096 + w * 512]);
      }
      if (stg && p == 1) {
        gl_lds16(pBh + 32, &lds[2][nb][w * 512]);
        gl_lds16(pBh + 32 + 128 * (long)ldb, &lds[2][nb][4096 + w * 512]);
        gl_lds16(pBl + 32, &lds[3][nb][w * 512]);
        gl_lds16(pBl + 32 + 128 * (long)ldb, &lds[3][nb][4096 + w * 512]);
      }
      __builtin_amdgcn_s_barrier();
      __builtin_amdgcn_s_setprio(1);
#pragma unroll
      for (int i = 0; i < 2; ++i) {
        const int mi = 2 * p + i;
#pragma unroll
        for (int ni = 0; ni < 4; ++ni) {
          acc[mi][ni] = __builtin_amdgcn_mfma_f32_16x16x32_bf16(ah[i], bh[ni], acc[mi][ni], 0, 0, 0);
          acc[mi][ni] = __builtin_amdgcn_mfma_f32_16x16x32_bf16(ah[i], bl[ni], acc[mi][ni], 0, 0, 0);
          acc[mi][ni] = __builtin_amdgcn_mfma_f32_16x16x32_bf16(al[i], bh[ni], acc[mi][ni], 0, 0, 0);
        }
      }
      __builtin_amdgcn_s_setprio(0);
      if (p < 3) __builtin_amdgcn_s_barrier();
    }
    asm volatile("s_waitcnt vmcnt(0)" ::: "memory");
    __syncthreads();
    pAh += 32; pAl += 32; pBh += 32; pBl += 32;
  }

  // Epilogue: scores = acc*scale + mask_filled^T.
  if (maskT) {
#pragma unroll
    for (int mi = 0; mi < 8; ++mi) {
#pragma unroll
      for (int ni = 0; ni < 4; ++ni) {
        long row0q = bm + wr * 128 + mi * 16 + g * 4;
        long col = bn + wc * 64 + ni * 16 + r;
#pragma unroll
        for (int q = 0; q < 4; ++q) {
          long row = row0q + q;
          float mv = bf2f(maskT[row * (long)S_LEN + col]);
          C[row * (long)ldc + col] = acc[mi][ni][q] * scale + mv;
        }
      }
    }
  } else {
#pragma unroll
    for (int mi = 0; mi < 8; ++mi) {
#pragma unroll
      for (int ni = 0; ni < 4; ++ni) {
        long row0q = bm + wr * 128 + mi * 16 + g * 4;
        long col = bn + wc * 64 + ni * 16 + r;
#pragma unroll
        for (int q = 0; q < 4; ++q) {
          long row = row0q + q;
          float mv = mask[col * (long)S_LEN + row];
          float v = acc[mi][ni][q] * scale;
          v = (mv == 0.0f) ? -__builtin_inff() : (v + mv);
          C[row * (long)ldc + col] = v;
        }
      }
    }
  }
}

// ---------------------------------------------------------------------------
// Row softmax, IN PLACE: reads 4096 fp32 of row blockIdx.x, writes 4096 bf16
// into the first half of the same row (row stride 8192 ushorts).
__launch_bounds__(256)
__global__ void softmax_rows(float* __restrict__ Sc) {
  const long row = blockIdx.x;
  float* sr = Sc + row * (long)S_LEN;
  unsigned short* pr = (unsigned short*)sr;
  const int t = threadIdx.x;
  const int lane = t & 63, wid = t >> 6;

  float4 x[4];
  float m = -3.0e38f;
#pragma unroll
  for (int i = 0; i < 4; ++i) {
    x[i] = reinterpret_cast<const float4*>(sr)[t + i * 256];
    m = fmaxf(m, fmaxf(fmaxf(x[i].x, x[i].y), fmaxf(x[i].z, x[i].w)));
  }
#pragma unroll
  for (int o = 32; o; o >>= 1) m = fmaxf(m, __shfl_xor(m, o));
  __shared__ float redm[4];
  __shared__ float reds[4];
  if (lane == 0) redm[wid] = m;
  __syncthreads();
  m = fmaxf(fmaxf(redm[0], redm[1]), fmaxf(redm[2], redm[3]));

  float e[16];
  float s = 0.f;
#pragma unroll
  for (int i = 0; i < 4; ++i) {
    e[i * 4 + 0] = __expf(x[i].x - m);
    e[i * 4 + 1] = __expf(x[i].y - m);
    e[i * 4 + 2] = __expf(x[i].z - m);
    e[i * 4 + 3] = __expf(x[i].w - m);
    s += e[i * 4 + 0] + e[i * 4 + 1] + e[i * 4 + 2] + e[i * 4 + 3];
  }
#pragma unroll
  for (int o = 32; o; o >>= 1) s += __shfl_xor(s, o);
  if (lane == 0) reds[wid] = s;
  __syncthreads();
  s = reds[0] + reds[1] + reds[2] + reds[3];
  float inv = 1.0f / s;
#pragma unroll
  for (int i = 0; i < 4; ++i) {
    ushort4 o4;
    o4.x = f2bf(e[i * 4 + 0] * inv);
    o4.y = f2bf(e[i * 4 + 1] * inv);
    o4.z = f2bf(e[i * 4 + 2] * inv);
    o4.w = f2bf(e[i * 4 + 3] * inv);
    reinterpret_cast<ushort4*>(pr)[t + i * 256] = o4;
  }
}

// ---------------------------------------------------------------------------
extern "C" void kernel_launch(void* const* d_in, const int* in_sizes, int n_in,
                              void* d_out, int out_size, void* d_ws, size_t ws_size,
                              hipStream_t stream) {
  const float* emb  = (const float*)d_in[0];
  const float* mask = (const float*)d_in[1];
  const float* wq   = (const float*)d_in[2];
  const float* wk   = (const float*)d_in[3];
  const float* wv   = (const float*)d_in[4];
  float* out = (float*)d_out;
  char* ws = (char*)d_ws;

  const long SEG = 4096L * 1024;  // per-batch element count for E/QM/Vt

  // Tier A layout (need3 = 190,840,832 B):
  //  0          Eh[2]  16,777,216
  //  16777216   El[2]  16,777,216
  //  33554432   QMh[2] 16,777,216
  //  50331648   QMl[2] 16,777,216
  //  67108864   Vt[2]  16,777,216
  //  83886080   MtH     2,097,152
  //  85983232   MtL     2,097,152
  //  88080384   Wvt     2,097,152
  //  90177536   scores 67,108,864  (weight hi/lo splits alias its start)
  //  157286400  maskT  33,554,432
  const size_t need3 = 190840832;
  // Tier B: round-17 layout (106,954,752 proven; +maskT optional).
  const size_t need = 106954752;
  const size_t need2 = need + (size_t)S_LEN * S_LEN * 2;
  if (ws_size < need) return;

  if (ws_size >= need3) {
    // ---------------- Tier A: batched z=2 ----------------
    unsigned short* Eh  = (unsigned short*)(ws);
    unsigned short* El  = (unsigned short*)(ws + 16777216);
    unsigned short* QMh = (unsigned short*)(ws + 33554432);
    unsigned short* QMl = (unsigned short*)(ws + 50331648);
    unsigned short* Vt  = (unsigned short*)(ws + 67108864);
    unsigned short* MtH = (unsigned short*)(ws + 83886080);
    unsigned short* MtL = (unsigned short*)(ws + 85983232);
    unsigned short* Wvt = (unsigned short*)(ws + 88080384);
    float* scores       = (float*)(ws + 90177536);
    unsigned short* WqH = (unsigned short*)(ws + 90177536);
    unsigned short* WqL = (unsigned short*)(ws + 90177536 + 2097152);
    unsigned short* WkH = (unsigned short*)(ws + 90177536 + 4194304);
    unsigned short* WkL = (unsigned short*)(ws + 90177536 + 6291456);
    unsigned short* maskT = (unsigned short*)(ws + 157286400);

    splitW<<<2048, 256, 0, stream>>>(wq, wk, WqH, WqL, WkH, WkL);
    prep_wv<<<dim3(32, 32), dim3(32, 8), 0, stream>>>(wv, Wvt);
    prep_maskT<<<dim3(128, 128), dim3(32, 8), 0, stream>>>(mask, maskT);
    gemm_bt<1, 0, 2, 64><<<dim3(16, 8), 256, 0, stream>>>(
        WkH, WkL, 1024, WqH, WqL, 1024, (void*)MtH, 1024, MtL, 32, 0, 0, 0);
    // split both batches in one dispatch (emb contiguous [2][4096][1024])
    split32<<<8192, 256, 0, stream>>>(emb, Eh, El);
    // QM for both batches (z=2)
    gemm_bt<1, 0, 2, 64><<<dim3(64, 8, 2), 256, 0, stream>>>(
        Eh, El, 1024, MtH, MtL, 1024, (void*)QMh, 1024, QMl, 32, SEG, 0, SEG);
    // Vt for both batches (z=2, KU=4)
    gemm_bt<0, 2, 4, 64><<<dim3(16, 32, 2), 256, 0, stream>>>(
        Wvt, nullptr, 1024, Eh, nullptr, 1024, (void*)Vt, 4096, nullptr, 32, 0, SEG, SEG);
    for (int b = 0; b < 2; ++b) {
      float* outb = out + (size_t)b * SEG;
      gemm8s<<<dim3(16, 16), 512, 0, stream>>>(
          QMh + b * SEG, QMl + b * SEG, 1024, Eh + b * SEG, El + b * SEG, 1024,
          scores, 4096, mask, maskT, 0.03125f, 32);
      softmax_rows<<<4096, 256, 0, stream>>>(scores);
      gemm_bt<0, 3, 4, 64><<<dim3(64, 8), 256, 0, stream>>>(
          (unsigned short*)scores, nullptr, 8192, Vt + b * SEG, nullptr, 4096,
          (void*)outb, 1024, nullptr, 128, 0, 0, 0);
    }
    return;
  }

  // ---------------- Tier B: round-17 sequential (proven) ----------------
  const bool useT = (ws_size >= need2);
  unsigned short* Eh  = (unsigned short*)(ws);
  unsigned short* El  = (unsigned short*)(ws + 8388608);
  unsigned short* QMh = (unsigned short*)(ws + 16777216);
  unsigned short* QMl = (unsigned short*)(ws + 25165824);
  unsigned short* Vt  = QMh;  // alias, live only after scores
  unsigned short* MtH = (unsigned short*)(ws + 33554432);
  unsigned short* MtL = (unsigned short*)(ws + 35651584);
  unsigned short* Wvt = (unsigned short*)(ws + 37748736);
  float* scores       = (float*)(ws + 39845888);
  unsigned short* WqH = (unsigned short*)(ws + 39845888);
  unsigned short* WqL = (unsigned short*)(ws + 39845888 + 2097152);
  unsigned short* WkH = (unsigned short*)(ws + 39845888 + 4194304);
  unsigned short* WkL = (unsigned short*)(ws + 39845888 + 6291456);
  unsigned short* maskT = useT ? (unsigned short*)(ws + need) : nullptr;

  splitW<<<2048, 256, 0, stream>>>(wq, wk, WqH, WqL, WkH, WkL);
  prep_wv<<<dim3(32, 32), dim3(32, 8), 0, stream>>>(wv, Wvt);
  if (useT)
    prep_maskT<<<dim3(128, 128), dim3(32, 8), 0, stream>>>(mask, maskT);
  gemm_bt<1, 0, 2, 64><<<dim3(16, 8), 256, 0, stream>>>(
      WkH, WkL, 1024, WqH, WqL, 1024, (void*)MtH, 1024, MtL, 32, 0, 0, 0);

  for (int b = 0; b < 2; ++b) {
    const float* embb = emb + (size_t)b * SEG;
    float* outb = out + (size_t)b * SEG;
    split32<<<4096, 256, 0, stream>>>(embb, Eh, El);
    gemm_bt<1, 0, 2, 64><<<dim3(64, 8), 256, 0, stream>>>(
        Eh, El, 1024, MtH, MtL, 1024, (void*)QMh, 1024, QMl, 32, 0, 0, 0);
    gemm8s<<<dim3(16, 16), 512, 0, stream>>>(
        QMh, QMl, 1024, Eh, El, 1024, scores, 4096, mask, maskT, 0.03125f, 32);
    gemm_bt<0, 2, 4, 64><<<dim3(16, 32), 256, 0, stream>>>(
        Wvt, nullptr, 1024, Eh, nullptr, 1024, (void*)Vt, 4096, nullptr, 32, 0, 0, 0);
    softmax_rows<<<4096, 256, 0, stream>>>(scores);
    gemm_bt<0, 3, 4, 64><<<dim3(64, 8), 256, 0, stream>>>(
        (unsigned short*)scores, nullptr, 8192, Vt, nullptr, 4096,
        (void*)outb, 1024, nullptr, 128, 0, 0, 0);
  }
}

// Round 19
// 477.785 us; speedup vs baseline: 1.0110x; 1.0110x over previous
//
#include <hip/hip_runtime.h>

// Self-attention B=2, S=4096, D=1024, fp32 in/out.
//
// Round-19: REVERT to round-17 exactly (478.6us best). Round-18's Tier-A
// batching regressed (483.1): the 191MB cycled workspace pressed L3 and
// slowed gemm8s staging reads (hbm_gbps 1650->1570-1630) more than the
// gap/TLP savings. Sequential batches + compact 140MB layout restored.
//
// Final configuration (all proven by within-session A/B):
//   * QM trick: scores = (E*M)*E^T, Mt = Wq*Wk^T precomputed (r4/r5).
//   * Split-bf16 {hh,hl,lh} fp32 emulation for the precision-critical path.
//   * XOR-swizzled LDS (conflicts=0, coalescing intact) (r7).
//   * scores: 256^2 8-wave 4-phase dbuf, staging A@p0/B@p1, setprio (r9/r12).
//   * bf16 maskT epilogue, -inf pre-encoded (r9).
//   * BM=64 TLP tiles for QM/Vt/PV (r13); KU=2 SPLIT, KU=4 PV (r15/r17).

#define S_LEN 4096

typedef __bf16 bf16x8 __attribute__((ext_vector_type(8)));
typedef float f32x4 __attribute__((ext_vector_type(4)));

__device__ __forceinline__ unsigned short f2bf(float x) {
  unsigned u = __float_as_uint(x);
  unsigned r = u + 0x7fffu + ((u >> 16) & 1u);  // round-to-nearest-even
  return (unsigned short)(r >> 16);
}
__device__ __forceinline__ float bf2f(unsigned short h) {
  return __uint_as_float(((unsigned)h) << 16);
}

__device__ __forceinline__ void gl_lds16(const void* g, void* l) {
  __builtin_amdgcn_global_load_lds(
      (const __attribute__((address_space(1))) void*)g,
      (__attribute__((address_space(3))) void*)l, 16, 0, 0);
}

// ---------------------------------------------------------------------------
// split32: fp32 -> (hi, lo) bf16 pair, elementwise, float4-vectorized.
__launch_bounds__(256)
__global__ void split32(const float* __restrict__ e,
                        unsigned short* __restrict__ Eh,
                        unsigned short* __restrict__ El) {
  int i = blockIdx.x * 256 + threadIdx.x;  // float4 index
  float4 v = reinterpret_cast<const float4*>(e)[i];
  ushort4 h, l;
  h.x = f2bf(v.x); l.x = f2bf(v.x - bf2f(h.x));
  h.y = f2bf(v.y); l.y = f2bf(v.y - bf2f(h.y));
  h.z = f2bf(v.z); l.z = f2bf(v.z - bf2f(h.z));
  h.w = f2bf(v.w); l.w = f2bf(v.w - bf2f(h.w));
  reinterpret_cast<ushort4*>(Eh)[i] = h;
  reinterpret_cast<ushort4*>(El)[i] = l;
}

// splitW: wq and wk hi/lo split in one dispatch (grid 2048; 262144 float4 each).
__launch_bounds__(256)
__global__ void splitW(const float* __restrict__ wq, const float* __restrict__ wk,
                       unsigned short* __restrict__ WqH, unsigned short* __restrict__ WqL,
                       unsigned short* __restrict__ WkH, unsigned short* __restrict__ WkL) {
  int i = blockIdx.x * 256 + threadIdx.x;
  const bool isQ = (i < 262144);
  const float* s = isQ ? wq : wk;
  unsigned short* H = isQ ? WqH : WkH;
  unsigned short* L = isQ ? WqL : WkL;
  int j = isQ ? i : i - 262144;
  float4 v = reinterpret_cast<const float4*>(s)[j];
  ushort4 h, l;
  h.x = f2bf(v.x); l.x = f2bf(v.x - bf2f(h.x));
  h.y = f2bf(v.y); l.y = f2bf(v.y - bf2f(h.y));
  h.z = f2bf(v.z); l.z = f2bf(v.z - bf2f(h.z));
  h.w = f2bf(v.w); l.w = f2bf(v.w - bf2f(h.w));
  reinterpret_cast<ushort4*>(H)[j] = h;
  reinterpret_cast<ushort4*>(L)[j] = l;
}

// ---------------------------------------------------------------------------
// prep_wv: Wv[d][e] -> Wvt[e][d] plain bf16. 32x32 LDS transpose.
__launch_bounds__(256)
__global__ void prep_wv(const float* __restrict__ wv, unsigned short* __restrict__ Wvt) {
  __shared__ float tile[32][33];
  const int bx = blockIdx.x * 32;
  const int by = blockIdx.y * 32;
  const int tx = threadIdx.x;
  const int ty = threadIdx.y;
#pragma unroll
  for (int j = 0; j < 4; ++j)
    tile[ty + j * 8][tx] = wv[(long)(by + ty + j * 8) * 1024 + bx + tx];
  __syncthreads();
#pragma unroll
  for (int j = 0; j < 4; ++j) {
    float v = tile[tx][ty + j * 8];
    Wvt[(long)(bx + ty + j * 8) * 1024 + by + tx] = f2bf(v);
  }
}

// ---------------------------------------------------------------------------
// prep_maskT: maskT[q][k] = bf16(mask_filled[k][q]), mask==0 -> -inf (0xFF80).
__launch_bounds__(256)
__global__ void prep_maskT(const float* __restrict__ mask,
                           unsigned short* __restrict__ maskT) {
  __shared__ float tile[32][33];
  const int bx = blockIdx.x * 32;  // q block
  const int by = blockIdx.y * 32;  // k block
  const int tx = threadIdx.x;
  const int ty = threadIdx.y;
#pragma unroll
  for (int j = 0; j < 4; ++j)
    tile[ty + j * 8][tx] = mask[(long)(by + ty + j * 8) * S_LEN + bx + tx];
  __syncthreads();
#pragma unroll
  for (int j = 0; j < 4; ++j) {
    float v = tile[tx][ty + j * 8];  // = mask[by+tx][bx+ty+j*8]
    unsigned short u = (v == 0.0f) ? (unsigned short)0xFF80 : f2bf(v);
    maskT[(long)(bx + ty + j * 8) * S_LEN + by + tx] = u;
  }
}

// ---------------------------------------------------------------------------
// BMx128 engine: NT GEMM with XOR-swizzled LDS. KU = K-unroll, BM in {64,128}.
// 4 waves: wave tile (BM/2) x 64.  MODE 0: hi/lo pair  MODE 2: bf16  MODE 3: f32.
template <int SPLIT, int MODE, int KU, int BM>
__launch_bounds__(256)
__global__ void gemm_bt(const unsigned short* __restrict__ Ah,
                        const unsigned short* __restrict__ Al, int lda,
                        const unsigned short* __restrict__ Bh,
                        const unsigned short* __restrict__ Bl, int ldb,
                        void* __restrict__ Cp, int ldc,
                        unsigned short* __restrict__ C2, int kIters) {
  constexpr int NMI = BM / 32;        // fragment rows per wave (4 or 2)
  __shared__ unsigned short lAh[KU * BM * 32];
  __shared__ unsigned short lBh[KU * 128 * 32];
  __shared__ unsigned short lAl[SPLIT ? KU * BM * 32 : 8];   // KU-scaled
  __shared__ unsigned short lBl[SPLIT ? KU * 128 * 32 : 8];

  const int t = threadIdx.x;
  const int w = t >> 6;
  const int lane = t & 63;
  const int g = lane >> 4;
  const int r = lane & 15;
  const int wm = (w >> 1) * (BM / 2);
  const int wn = (w & 1) * 64;
  const long bm = (long)blockIdx.x * BM;
  const long bn = (long)blockIdx.y * 128;

  f32x4 acc[NMI][4];
  const f32x4 vzero = {0.f, 0.f, 0.f, 0.f};
#pragma unroll
  for (int mi = 0; mi < NMI; ++mi)
#pragma unroll
    for (int ni = 0; ni < 4; ++ni) acc[mi][ni] = vzero;

  const int outer = kIters / KU;
  for (int kt = 0; kt < outer; ++kt) {
    __syncthreads();
    const long kbase = (long)kt * 32 * KU;
#pragma unroll
    for (int u = 0; u < KU; ++u) {
      // A tile: BM*4 granules (1 or 2 passes of 256 threads)
#pragma unroll
      for (int i = 0; i < BM * 4 / 256; ++i) {
        int s = i * 256 + t;
        int row = s >> 2;
        int ko = (s & 3) ^ ((row >> 1) & 3);
        long goffA = (bm + row) * (long)lda + kbase + u * 32 + ko * 8;
        int lbase = u * (BM * 32) + i * 2048 + w * 512;
        gl_lds16(Ah + goffA, lAh + lbase);
        if constexpr (SPLIT) gl_lds16(Al + goffA, lAl + lbase);
      }
      // B tile: 512 granules (2 passes)
#pragma unroll
      for (int i = 0; i < 2; ++i) {
        int s = i * 256 + t;
        int row = s >> 2;
        int ko = (s & 3) ^ ((row >> 1) & 3);
        long goffB = (bn + row) * (long)ldb + kbase + u * 32 + ko * 8;
        int lbase = u * 4096 + i * 2048 + w * 512;
        gl_lds16(Bh + goffB, lBh + lbase);
        if constexpr (SPLIT) gl_lds16(Bl + goffB, lBl + lbase);
      }
    }
    __syncthreads();

#pragma unroll
    for (int u = 0; u < KU; ++u) {
      bf16x8 af[NMI], bfh[4], af2[NMI], bf2v[4];
#pragma unroll
      for (int mi = 0; mi < NMI; ++mi) {
        int rowa = wm + mi * 16 + r;
        int o = u * (BM * 32) + rowa * 32 + ((g ^ ((rowa >> 1) & 3)) * 8);
        af[mi] = *reinterpret_cast<const bf16x8*>(&lAh[o]);
        if constexpr (SPLIT)
          af2[mi] = *reinterpret_cast<const bf16x8*>(&lAl[o]);
      }
#pragma unroll
      for (int ni = 0; ni < 4; ++ni) {
        int rowb = wn + ni * 16 + r;
        int o = u * 4096 + rowb * 32 + ((g ^ ((rowb >> 1) & 3)) * 8);
        bfh[ni] = *reinterpret_cast<const bf16x8*>(&lBh[o]);
        if constexpr (SPLIT)
          bf2v[ni] = *reinterpret_cast<const bf16x8*>(&lBl[o]);
      }
#pragma unroll
      for (int mi = 0; mi < NMI; ++mi)
#pragma unroll
        for (int ni = 0; ni < 4; ++ni) {
          acc[mi][ni] = __builtin_amdgcn_mfma_f32_16x16x32_bf16(af[mi], bfh[ni], acc[mi][ni], 0, 0, 0);
          if constexpr (SPLIT) {
            acc[mi][ni] = __builtin_amdgcn_mfma_f32_16x16x32_bf16(af[mi], bf2v[ni], acc[mi][ni], 0, 0, 0);
            acc[mi][ni] = __builtin_amdgcn_mfma_f32_16x16x32_bf16(af2[mi], bfh[ni], acc[mi][ni], 0, 0, 0);
          }
        }
    }
  }

#pragma unroll
  for (int mi = 0; mi < NMI; ++mi) {
#pragma unroll
    for (int ni = 0; ni < 4; ++ni) {
      long row0 = bm + wm + mi * 16 + g * 4;
      long col = bn + wn + ni * 16 + r;
#pragma unroll
      for (int q = 0; q < 4; ++q) {
        float v = acc[mi][ni][q];
        long row = row0 + q;
        if constexpr (MODE == 0) {
          unsigned short h = f2bf(v);
          ((unsigned short*)Cp)[row * (long)ldc + col] = h;
          C2[row * (long)ldc + col] = f2bf(v - bf2f(h));
        } else if constexpr (MODE == 2) {
          ((unsigned short*)Cp)[row * (long)ldc + col] = f2bf(v);
        } else {
          ((float*)Cp)[row * (long)ldc + col] = v;
        }
      }
    }
  }
}

// ---------------------------------------------------------------------------
// Scores kernel (round-15-proven, 16x16x32): 256^2, 8 waves (2M x 4N),
// BK=32, 2-stage LDS dbuf, 4 phases/K-step, staging A@p0 B@p1.
__launch_bounds__(512, 2)
__global__ void gemm8s(const unsigned short* __restrict__ Ah,
                       const unsigned short* __restrict__ Al, int lda,
                       const unsigned short* __restrict__ Bh,
                       const unsigned short* __restrict__ Bl, int ldb,
                       float* __restrict__ C, int ldc,
                       const float* __restrict__ mask,
                       const unsigned short* __restrict__ maskT,
                       float scale, int nkt) {
  __shared__ __align__(16) unsigned short lds[4][2][8192];

  const int t = threadIdx.x;          // 0..511
  const int w = t >> 6;               // wave 0..7
  const int lane = t & 63;
  const int g = lane >> 4;
  const int r = lane & 15;
  const int wr = w >> 2;              // 0..1  (M)
  const int wc = w & 3;               // 0..3  (N)
  const long bm = (long)blockIdx.x * 256;
  const long bn = (long)blockIdx.y * 256;

  const int row0 = t >> 2;
  const int ko = (t & 3) ^ ((t >> 3) & 3);
  const unsigned short* pAh = Ah + (bm + row0) * (long)lda + ko * 8;
  const unsigned short* pAl = Al + (bm + row0) * (long)lda + ko * 8;
  const unsigned short* pBh = Bh + (bn + row0) * (long)ldb + ko * 8;
  const unsigned short* pBl = Bl + (bn + row0) * (long)ldb + ko * 8;

  f32x4 acc[8][4];
  const f32x4 vzero = {0.f, 0.f, 0.f, 0.f};
#pragma unroll
  for (int mi = 0; mi < 8; ++mi)
#pragma unroll
    for (int ni = 0; ni < 4; ++ni) acc[mi][ni] = vzero;

  // Prologue: stage K-step 0 into buf 0.
#pragma unroll
  for (int T = 0; T < 4; ++T) {
    const unsigned short* sp = (T == 0) ? pAh : (T == 1) ? pAl : (T == 2) ? pBh : pBl;
    long ld = (T < 2) ? lda : ldb;
    gl_lds16(sp, &lds[T][0][w * 512]);
    gl_lds16(sp + 128 * ld, &lds[T][0][4096 + w * 512]);
  }
  asm volatile("s_waitcnt vmcnt(0)" ::: "memory");
  __syncthreads();

  for (int kt = 0; kt < nkt; ++kt) {
    const int cb = kt & 1, nb = cb ^ 1;
    const bool stg = (kt < nkt - 1);
    bf16x8 bh[4], bl[4];
#pragma unroll
    for (int p = 0; p < 4; ++p) {
      if (p == 0) {
#pragma unroll
        for (int ni = 0; ni < 4; ++ni) {
          int rowb = wc * 64 + ni * 16 + r;
          int o = rowb * 32 + ((g ^ ((rowb >> 1) & 3)) * 8);
          bh[ni] = *reinterpret_cast<const bf16x8*>(&lds[2][cb][o]);
          bl[ni] = *reinterpret_cast<const bf16x8*>(&lds[3][cb][o]);
        }
      }
      bf16x8 ah[2], al[2];
#pragma unroll
      for (int i = 0; i < 2; ++i) {
        int rowa = wr * 128 + (2 * p + i) * 16 + r;
        int o = rowa * 32 + ((g ^ ((rowa >> 1) & 3)) * 8);
        ah[i] = *reinterpret_cast<const bf16x8*>(&lds[0][cb][o]);
        al[i] = *reinterpret_cast<const bf16x8*>(&lds[1][cb][o]);
      }
      // Staging: A tiles at phase 0, B tiles at phase 1 (round-9-proven).
      if (stg && p == 0) {
        gl_lds16(pAh + 32, &lds[0][nb][w * 512]);
        gl_lds16(pAh + 32 + 128 * (long)lda, &lds[0][nb][4096 + w * 512]);
        gl_lds16(pAl + 32, &lds[1][nb][w * 512]);
        gl_lds16(pAl + 32 + 128 * (long)lda, &lds[1][nb][4096 + w * 512]);
      }
      if (stg && p == 1) {
        gl_lds16(pBh + 32, &lds[2][nb][w * 512]);
        gl_lds16(pBh + 32 + 128 * (long)ldb, &lds[2][nb][4096 + w * 512]);
        gl_lds16(pBl + 32, &lds[3][nb][w * 512]);
        gl_lds16(pBl + 32 + 128 * (long)ldb, &lds[3][nb][4096 + w * 512]);
      }
      __builtin_amdgcn_s_barrier();
      __builtin_amdgcn_s_setprio(1);
#pragma unroll
      for (int i = 0; i < 2; ++i) {
        const int mi = 2 * p + i;
#pragma unroll
        for (int ni = 0; ni < 4; ++ni) {
          acc[mi][ni] = __builtin_amdgcn_mfma_f32_16x16x32_bf16(ah[i], bh[ni], acc[mi][ni], 0, 0, 0);
          acc[mi][ni] = __builtin_amdgcn_mfma_f32_16x16x32_bf16(ah[i], bl[ni], acc[mi][ni], 0, 0, 0);
          acc[mi][ni] = __builtin_amdgcn_mfma_f32_16x16x32_bf16(al[i], bh[ni], acc[mi][ni], 0, 0, 0);
        }
      }
      __builtin_amdgcn_s_setprio(0);
      if (p < 3) __builtin_amdgcn_s_barrier();
    }
    asm volatile("s_waitcnt vmcnt(0)" ::: "memory");
    __syncthreads();
    pAh += 32; pAl += 32; pBh += 32; pBl += 32;
  }

  // Epilogue: scores = acc*scale + mask_filled^T.
  if (maskT) {
#pragma unroll
    for (int mi = 0; mi < 8; ++mi) {
#pragma unroll
      for (int ni = 0; ni < 4; ++ni) {
        long row0q = bm + wr * 128 + mi * 16 + g * 4;
        long col = bn + wc * 64 + ni * 16 + r;
#pragma unroll
        for (int q = 0; q < 4; ++q) {
          long row = row0q + q;
          float mv = bf2f(maskT[row * (long)S_LEN + col]);
          C[row * (long)ldc + col] = acc[mi][ni][q] * scale + mv;
        }
      }
    }
  } else {
#pragma unroll
    for (int mi = 0; mi < 8; ++mi) {
#pragma unroll
      for (int ni = 0; ni < 4; ++ni) {
        long row0q = bm + wr * 128 + mi * 16 + g * 4;
        long col = bn + wc * 64 + ni * 16 + r;
#pragma unroll
        for (int q = 0; q < 4; ++q) {
          long row = row0q + q;
          float mv = mask[col * (long)S_LEN + row];
          float v = acc[mi][ni][q] * scale;
          v = (mv == 0.0f) ? -__builtin_inff() : (v + mv);
          C[row * (long)ldc + col] = v;
        }
      }
    }
  }
}

// ---------------------------------------------------------------------------
// Row softmax, IN PLACE: reads 4096 fp32 of row blockIdx.x, writes 4096 bf16
// into the first half of the same row (row stride 8192 ushorts).
__launch_bounds__(256)
__global__ void softmax_rows(float* __restrict__ Sc) {
  const long row = blockIdx.x;
  float* sr = Sc + row * (long)S_LEN;
  unsigned short* pr = (unsigned short*)sr;
  const int t = threadIdx.x;
  const int lane = t & 63, wid = t >> 6;

  float4 x[4];
  float m = -3.0e38f;
#pragma unroll
  for (int i = 0; i < 4; ++i) {
    x[i] = reinterpret_cast<const float4*>(sr)[t + i * 256];
    m = fmaxf(m, fmaxf(fmaxf(x[i].x, x[i].y), fmaxf(x[i].z, x[i].w)));
  }
#pragma unroll
  for (int o = 32; o; o >>= 1) m = fmaxf(m, __shfl_xor(m, o));
  __shared__ float redm[4];
  __shared__ float reds[4];
  if (lane == 0) redm[wid] = m;
  __syncthreads();
  m = fmaxf(fmaxf(redm[0], redm[1]), fmaxf(redm[2], redm[3]));

  float e[16];
  float s = 0.f;
#pragma unroll
  for (int i = 0; i < 4; ++i) {
    e[i * 4 + 0] = __expf(x[i].x - m);
    e[i * 4 + 1] = __expf(x[i].y - m);
    e[i * 4 + 2] = __expf(x[i].z - m);
    e[i * 4 + 3] = __expf(x[i].w - m);
    s += e[i * 4 + 0] + e[i * 4 + 1] + e[i * 4 + 2] + e[i * 4 + 3];
  }
#pragma unroll
  for (int o = 32; o; o >>= 1) s += __shfl_xor(s, o);
  if (lane == 0) reds[wid] = s;
  __syncthreads();
  s = reds[0] + reds[1] + reds[2] + reds[3];
  float inv = 1.0f / s;
#pragma unroll
  for (int i = 0; i < 4; ++i) {
    ushort4 o4;
    o4.x = f2bf(e[i * 4 + 0] * inv);
    o4.y = f2bf(e[i * 4 + 1] * inv);
    o4.z = f2bf(e[i * 4 + 2] * inv);
    o4.w = f2bf(e[i * 4 + 3] * inv);
    reinterpret_cast<ushort4*>(pr)[t + i * 256] = o4;
  }
}

// ---------------------------------------------------------------------------
extern "C" void kernel_launch(void* const* d_in, const int* in_sizes, int n_in,
                              void* d_out, int out_size, void* d_ws, size_t ws_size,
                              hipStream_t stream) {
  const float* emb  = (const float*)d_in[0];
  const float* mask = (const float*)d_in[1];
  const float* wq   = (const float*)d_in[2];
  const float* wk   = (const float*)d_in[3];
  const float* wv   = (const float*)d_in[4];
  float* out = (float*)d_out;
  char* ws = (char*)d_ws;

  // Workspace: rounds 4-17 layout (106,954,752, proven) plus optional maskT
  // [4096][4096] bf16 (need2 = 140,509,184; proven rounds 9-17).
  const size_t need = 106954752;
  const size_t need2 = need + (size_t)S_LEN * S_LEN * 2;
  if (ws_size < need) return;
  const bool useT = (ws_size >= need2);

  unsigned short* Eh  = (unsigned short*)(ws);
  unsigned short* El  = (unsigned short*)(ws + 8388608);
  unsigned short* QMh = (unsigned short*)(ws + 16777216);
  unsigned short* QMl = (unsigned short*)(ws + 25165824);
  unsigned short* Vt  = QMh;  // alias, live only after scores
  unsigned short* MtH = (unsigned short*)(ws + 33554432);
  unsigned short* MtL = (unsigned short*)(ws + 35651584);
  unsigned short* Wvt = (unsigned short*)(ws + 37748736);
  float* scores       = (float*)(ws + 39845888);
  unsigned short* WqH = (unsigned short*)(ws + 39845888);
  unsigned short* WqL = (unsigned short*)(ws + 39845888 + 2097152);
  unsigned short* WkH = (unsigned short*)(ws + 39845888 + 4194304);
  unsigned short* WkL = (unsigned short*)(ws + 39845888 + 6291456);
  unsigned short* maskT = useT ? (unsigned short*)(ws + need) : nullptr;

  // ---- once: split weights (merged), transpose Wv (+mask), precompute Mt --
  splitW<<<2048, 256, 0, stream>>>(wq, wk, WqH, WqL, WkH, WkL);
  prep_wv<<<dim3(32, 32), dim3(32, 8), 0, stream>>>(wv, Wvt);
  if (useT)
    prep_maskT<<<dim3(128, 128), dim3(32, 8), 0, stream>>>(mask, maskT);
  // Mt[d'][d] = sum_e Wk[d'][e]*Wq[d][e]: SPLIT, BM=64, KU=2 (grid 128).
  gemm_bt<1, 0, 2, 64><<<dim3(16, 8), 256, 0, stream>>>(
      WkH, WkL, 1024, WqH, WqL, 1024, (void*)MtH, 1024, MtL, 32);

  for (int b = 0; b < 2; ++b) {
    const float* embb = emb + (size_t)b * 4096 * 1024;
    float* outb = out + (size_t)b * 4096 * 1024;

    // 1) split embeddings into bf16 hi/lo
    split32<<<4096, 256, 0, stream>>>(embb, Eh, El);
    // 2) QM = E*Mt^T (SPLIT, BM=64, KU=2 -> grid 512, 48KB LDS), hi/lo store
    gemm_bt<1, 0, 2, 64><<<dim3(64, 8), 256, 0, stream>>>(
        Eh, El, 1024, MtH, MtL, 1024, (void*)QMh, 1024, QMl, 32);
    // 3) scores = (QM * E^T)/32 + mask_filled^T  (256^2 8-wave engine)
    gemm8s<<<dim3(16, 16), 512, 0, stream>>>(
        QMh, QMl, 1024, Eh, El, 1024, scores, 4096, mask, maskT, 0.03125f, 32);
    // 4) Vt = Wvt * E^T (plain bf16, BK=64, BM=64 -> grid 512)
    gemm_bt<0, 2, 2, 64><<<dim3(16, 32), 256, 0, stream>>>(
        Wvt, nullptr, 1024, Eh, nullptr, 1024, (void*)Vt, 4096, nullptr, 32);
    // 5) row softmax -> P bf16, IN PLACE over scores rows (stride 8192 ushorts)
    softmax_rows<<<4096, 256, 0, stream>>>(scores);
    // 6) out = P @ V (plain, KU=4 / BK=128, BM=64 -> grid 512), fp32 store
    gemm_bt<0, 3, 4, 64><<<dim3(64, 8), 256, 0, stream>>>(
        (unsigned short*)scores, nullptr, 8192, Vt, nullptr, 4096,
        (void*)outb, 1024, nullptr, 128);
  }
}